// Round 2
// baseline (241.635 us; speedup 1.0000x reference)
//
#include <hip/hip_runtime.h>

// ACT module decomposition:
//   base = inputs + time_enc; state_k = base + pos_enc[k]
//   LN stats + halting collapse to per-token scalars (fp32, bit-exact branches)
//   tstate_k = Bt + Pt_k + bt with Bt = base@Wt^T  (ONE gemm, bf16 MFMA)
//   prev = S*(Bt+bt) + sum_k w_k*Pt_k
//
// Round-5 changes:
//   - token_kernel: sPos LDS staging dropped -> pos read from global (the 4
//     lane-groups of a wave broadcast-read the same 16B chunks; L1-served).
//     Occupancy cap 3 blocks/CU (48KB LDS) -> 4 blocks/CU (grid-limited).
//     Numerics bit-identical (same values, same order).
//   - pt_kernel + wtconv_kernel merged into ptwt_kernel: 1024 blocks, block =
//     one o-row; thread = one float4 of the row (short load chain, 4 blocks/CU
//     vs pt's 1 wave/SIMD latency trap); WtBF row emitted from the same load.
//   - gemm unchanged from round 4 (256x256 pipelined, counted vmcnt(8)).

#define Hdim 1024
#define Ntok 16384
#define Tdim 2048
#define KHOP 12

typedef unsigned short u16;
typedef __attribute__((ext_vector_type(8))) short bf16x8;
typedef __attribute__((ext_vector_type(4))) float floatx4;
struct __align__(8) u16x4 { u16 x, y, z, w; };

static __device__ inline u16 f2bf(float f) {
    union { float f; unsigned u; } x; x.f = f;
    unsigned r = x.u + 0x7FFFu + ((x.u >> 16) & 1u);   // RNE
    return (u16)(r >> 16);
}

// ---------------- kernel A1: per-k pos stats + gamma*wp array ----------------
// kst layout: [0..11] mu_pk, [12..23] ssp_k, [24..35] e_k, [36] gw, [37] bw
// UNCHANGED (its reduction order feeds the halting branch logits).
__global__ void kstats_kernel(const float* __restrict__ pos,
                              const float* __restrict__ gamma,
                              const float* __restrict__ beta,
                              const float* __restrict__ wp,
                              float* __restrict__ kst,
                              float* __restrict__ gwArr) {
    int lane = threadIdx.x; // 64 threads
    float gw = 0.f, bw = 0.f;
    for (int i = 0; i < 16; i++) {
        int h = lane + 64 * i;
        float g = gamma[h] * wp[h];
        gwArr[h] = g;
        gw += g;
        bw += beta[h] * wp[h];
    }
    for (int off = 32; off > 0; off >>= 1) {
        gw += __shfl_xor(gw, off);
        bw += __shfl_xor(bw, off);
    }
    for (int k = 0; k < KHOP; k++) {
        float s = 0.f, ss = 0.f, pg = 0.f;
        for (int i = 0; i < 16; i++) {
            int h = lane + 64 * i;
            float v = pos[k * Hdim + h];
            s += v; ss += v * v; pg += v * gamma[h] * wp[h];
        }
        for (int off = 32; off > 0; off >>= 1) {
            s += __shfl_xor(s, off);
            ss += __shfl_xor(ss, off);
            pg += __shfl_xor(pg, off);
        }
        if (lane == 0) {
            float mu = s * (1.0f / Hdim);
            kst[k] = mu;
            kst[12 + k] = ss - (float)Hdim * mu * mu;
            kst[24 + k] = pg - mu * gw;
        }
    }
    if (lane == 0) { kst[36] = gw; kst[37] = bw; }
}

// ---------------- kernel A2: PT[k][o] = sum_h pos[k,h]*Wt[o,h]  +  Wt->bf16 --
// 1024 blocks x 256 thr; block = output row o. Thread owns one float4 of the
// row: 13 vector loads (Wt + 12 pos), 48 FMA, then block-reduce 12 partials.
// Emits WtBF[o] from the same Wt load (replaces wtconv_kernel's 4MB re-read).
__global__ __launch_bounds__(256)
void ptwt_kernel(const float* __restrict__ pos,
                 const float* __restrict__ Wt,
                 float* __restrict__ PT,
                 u16* __restrict__ WtBF) {
    __shared__ float red[4][KHOP];
    int o = blockIdx.x;
    int t = threadIdx.x, wave = t >> 6, lane = t & 63;

    float4 w = ((const float4*)(Wt + (size_t)o * Hdim))[t];
    u16x4 ob; ob.x = f2bf(w.x); ob.y = f2bf(w.y); ob.z = f2bf(w.z); ob.w = f2bf(w.w);
    ((u16x4*)(WtBF + (size_t)o * Hdim))[t] = ob;

    const float4* pos4 = (const float4*)pos;
    float acc[KHOP];
#pragma unroll
    for (int k = 0; k < KHOP; k++) {
        float4 p = pos4[k * 256 + t];
        acc[k] = w.x * p.x + w.y * p.y + w.z * p.z + w.w * p.w;
    }
#pragma unroll
    for (int k = 0; k < KHOP; k++)
        for (int off = 32; off > 0; off >>= 1) acc[k] += __shfl_xor(acc[k], off);
    if (lane == 0) {
#pragma unroll
        for (int k = 0; k < KHOP; k++) red[wave][k] = acc[k];
    }
    __syncthreads();
    if (t < KHOP)
        PT[t * Hdim + o] = red[0][t] + red[1][t] + red[2][t] + red[3][t];
}

// ---------------- kernel B: token stats + halting + base->bf16 ----------------
// 1024 blocks x 256 thr; block = 16 tokens, single pass.
// Wave handles 4 tokens: 16 lanes per token, 64 elems (16 float4) per lane.
// pos read from GLOBAL (no LDS): the wave's 4 groups read identical addresses
// (hardware broadcast, L1-resident working set 48KB+4KB).
__global__ __launch_bounds__(256)
void token_kernel(const float* __restrict__ inp, const float* __restrict__ tenc,
                  const float* __restrict__ pos, const float* __restrict__ gwArr,
                  const float* __restrict__ bp, const float* __restrict__ kst,
                  float* __restrict__ SS, float* __restrict__ WW,
                  float* __restrict__ tail, u16* __restrict__ baseBF) {
    int t = threadIdx.x;
    int wave = t >> 6, lane = t & 63;
    int grp = lane >> 4, s = lane & 15;
    int n = blockIdx.x * 16 + wave * 4 + grp;

    const float4* ip4 = (const float4*)(inp + (size_t)n * Hdim);
    const float4* tp4 = (const float4*)(tenc + (size_t)(n & (Tdim - 1)) * Hdim);
    u16x4* ob4 = (u16x4*)(baseBF + (size_t)n * Hdim);
    const float4* gw4 = (const float4*)gwArr;
    const float4* pos4 = (const float4*)pos;

    float sm = 0.f, ss = 0.f, d1 = 0.f;
    float dk[KHOP];
#pragma unroll
    for (int k = 0; k < KHOP; k++) dk[k] = 0.f;

#pragma unroll
    for (int i = 0; i < 16; i++) {
        int idx = s + 16 * i;          // float4 index within the token row
        float4 a = ip4[idx], b = tp4[idx];
        float4 v = make_float4(a.x + b.x, a.y + b.y, a.z + b.z, a.w + b.w);
        u16x4 o; o.x = f2bf(v.x); o.y = f2bf(v.y); o.z = f2bf(v.z); o.w = f2bf(v.w);
        ob4[idx] = o;
        sm += v.x + v.y + v.z + v.w;
        ss += v.x * v.x + v.y * v.y + v.z * v.z + v.w * v.w;
        float4 g = gw4[idx];           // global, L1-resident (4 KB shared)
        d1 += v.x * g.x + v.y * g.y + v.z * g.z + v.w * g.w;
#pragma unroll
        for (int k = 0; k < KHOP; k++) {
            float4 p = pos4[k * 256 + idx];   // broadcast across 4 groups
            dk[k] += v.x * p.x + v.y * p.y + v.z * p.z + v.w * p.w;
        }
    }
    // reduce across the 16 lanes of this token's group
#pragma unroll
    for (int off = 8; off > 0; off >>= 1) {
        sm += __shfl_xor(sm, off);
        ss += __shfl_xor(ss, off);
        d1 += __shfl_xor(d1, off);
#pragma unroll
        for (int k = 0; k < KHOP; k++) dk[k] += __shfl_xor(dk[k], off);
    }

    if (s == 0) {
        float gwv = kst[36], bwv = kst[37], bpv = bp[0];
        float mu = sm * (1.0f / Hdim);
        float ssb = ss - (float)Hdim * mu * mu;
        float hp = 0.f, rem = 0.f, nu = 0.f;
        float uw[KHOP];
#pragma unroll
        for (int k = 0; k < KHOP; k++) {
            float mup = kst[k], sspk = kst[12 + k], ek = kst[24 + k];
            float ck = dk[k] - (float)Hdim * mu * mup;
            float var = (ssb + sspk + 2.0f * ck) * (1.0f / Hdim);
            float inv = 1.0f / sqrtf(var + 1e-5f);
            float logit = inv * (d1 - mu * gwv + ek) + bwv + bpv;
            float p = 1.0f / (1.0f + expf(-logit));
            float sr = (hp < 1.0f) ? 1.0f : 0.0f;
            float acc = hp + p * sr;
            float nh = (acc > 0.9f) ? sr : 0.0f;
            float sr2 = (acc <= 0.9f) ? sr : 0.0f;
            hp += p * sr2;
            rem += nh * (1.0f - hp);
            hp += nh * rem;
            nu += sr2 + nh;
            uw[k] = p * sr2 + nh * rem;
        }
        float prod = 1.f, S = 0.f;
        float w[KHOP];
#pragma unroll
        for (int k = KHOP - 1; k >= 0; k--) {
            w[k] = uw[k] * prod;
            prod *= (1.0f - uw[k]);
            S += w[k];
        }
        SS[n] = S;
#pragma unroll
        for (int k = 0; k < KHOP; k++) WW[k * Ntok + n] = w[k];
        tail[n] = rem;
        tail[Ntok + n] = nu;
    }
}

// ---------------- kernel C: pipelined bf16 MFMA GEMM 256x256xBK64 ------------
// A = baseBF [M=16384, K=1024], Bt = WtBF [N=1024, K=1024] (both K-contiguous)
// out[m,o] = S[m]*(A@Bt^T + bt[o]) + sum_k WW[k][m]*PT[k][o]
//
// LDS (dynamic, 128KB): A slots at byte 0 / 32768, B slots at 65536 / 98304.
// Per slot: [256 rows][64 cols] bf16, row = 8 chunks of 16B; LDS chunk c of
// row r holds global chunk c ^ (r&7)  (involution; read applies same XOR).
// K-loop: 16 K-tiles; tile t+2 staged during group t+1; entry wait vmcnt(8)
// keeps the younger tile's 8 loads in flight across the barrier.
__global__ __launch_bounds__(512, 2)
void gemm_bf16(const u16* __restrict__ A, const u16* __restrict__ Bt,
               const float* __restrict__ bt, const float* __restrict__ PT,
               const float* __restrict__ SS, const float* __restrict__ WW,
               float* __restrict__ out) {
    extern __shared__ u16 lds[];   // 65536 u16 = 128 KB
    const int tid = threadIdx.x;
    const int bm = blockIdx.x;     // 0..63  (M tiles) — linear%8 == bm%8
    const int bn = blockIdx.y;     // 0..3   (N tiles) — A-panel siblings share XCD
    const int gm = bm * 256, gn = bn * 256;

    // ---- staging constants: thread t -> row sr=t>>3 (+64*i), chunk t&7 ----
    const int sr = tid >> 3;
    const int gchunk = ((tid & 7) ^ (sr & 7)) << 3;   // element offset in row
    const u16* aStage = A + (size_t)(gm + sr) * Hdim + gchunk;
    const u16* bStage = Bt + (size_t)(gn + sr) * Hdim + gchunk;
    char* ldsA = (char*)lds + (size_t)tid * 16;            // + s*32768 + i*8192
    char* ldsB = (char*)lds + 65536 + (size_t)tid * 16;

#define STAGE_TILE(kt_)                                                          \
    do {                                                                         \
        const int s_ = (kt_) & 1;                                                \
        const u16* ap_ = aStage + (kt_) * 64;                                    \
        const u16* bp_ = bStage + (kt_) * 64;                                    \
        char* la_ = ldsA + s_ * 32768;                                           \
        char* lb_ = ldsB + s_ * 32768;                                           \
        _Pragma("unroll")                                                        \
        for (int i_ = 0; i_ < 4; i_++) {                                         \
            __builtin_amdgcn_global_load_lds(                                    \
                (const __attribute__((address_space(1))) void*)(ap_ + (size_t)i_ * 64 * Hdim), \
                (__attribute__((address_space(3))) void*)(la_ + i_ * 8192), 16, 0, 0); \
            __builtin_amdgcn_global_load_lds(                                    \
                (const __attribute__((address_space(1))) void*)(bp_ + (size_t)i_ * 64 * Hdim), \
                (__attribute__((address_space(3))) void*)(lb_ + i_ * 8192), 16, 0, 0); \
        }                                                                        \
    } while (0)

    // ---- prologue: tiles 0 and 1 in flight (16 loads) ----
    STAGE_TILE(0);
    STAGE_TILE(1);

    const int wave = tid >> 6, lane = tid & 63;
    const int wr = wave >> 2, wc = wave & 3;       // 2x4 wave grid, 128x64 each
    const int quad = lane >> 4, l16 = lane & 15;
    const int xorl = l16 & 7;
    const int pos0 = ((quad ^ xorl) << 3);         // kk=0 chunk position (elems)
    const int pos1 = (((4 + quad) ^ xorl) << 3);   // kk=1
    const u16* aRd = lds + (size_t)(128 * wr + l16) * 64;
    const u16* bRd = lds + 32768 + (size_t)(64 * wc + l16) * 64;

    floatx4 acc[8][4];
#pragma unroll
    for (int i = 0; i < 8; i++)
#pragma unroll
        for (int j = 0; j < 4; j++) acc[i][j] = (floatx4)0.f;

#pragma unroll 2
    for (int kt = 0; kt < 16; kt++) {
        const int s = kt & 1;
        if (kt < 15) { asm volatile("s_waitcnt vmcnt(8)" ::: "memory"); }
        else         { asm volatile("s_waitcnt vmcnt(0)" ::: "memory"); }
        asm volatile("s_barrier" ::: "memory");    // tile kt fully in LDS

        const u16* aS = aRd + s * 16384;
        const u16* bS = bRd + s * 16384;
        bf16x8 a[4][2], b[4][2];
#pragma unroll
        for (int ni = 0; ni < 4; ni++) {
            b[ni][0] = *(const bf16x8*)&bS[ni * 1024 + pos0];
            b[ni][1] = *(const bf16x8*)&bS[ni * 1024 + pos1];
        }
#pragma unroll
        for (int mi = 0; mi < 4; mi++) {
            a[mi][0] = *(const bf16x8*)&aS[mi * 1024 + pos0];
            a[mi][1] = *(const bf16x8*)&aS[mi * 1024 + pos1];
        }
        __builtin_amdgcn_s_setprio(1);
#pragma unroll
        for (int kk = 0; kk < 2; kk++)
#pragma unroll
            for (int mi = 0; mi < 4; mi++)
#pragma unroll
                for (int ni = 0; ni < 4; ni++)
                    acc[mi][ni] = __builtin_amdgcn_mfma_f32_16x16x32_bf16(
                        a[mi][kk], b[ni][kk], acc[mi][ni], 0, 0, 0);
        __builtin_amdgcn_s_setprio(0);

        // rows 128..255 of the A half this wave owns
#pragma unroll
        for (int mi = 0; mi < 4; mi++) {
            a[mi][0] = *(const bf16x8*)&aS[4096 + mi * 1024 + pos0];
            a[mi][1] = *(const bf16x8*)&aS[4096 + mi * 1024 + pos1];
        }
        // all reads of slot s issued by every wave -> safe to overwrite:
        // stage loads land >=~250cy after issue, reads complete in ~50cy.
        asm volatile("s_barrier" ::: "memory");
        if (kt < 14) STAGE_TILE(kt + 2);
        __builtin_amdgcn_s_setprio(1);
#pragma unroll
        for (int kk = 0; kk < 2; kk++)
#pragma unroll
            for (int mi = 0; mi < 4; mi++)
#pragma unroll
                for (int ni = 0; ni < 4; ni++)
                    acc[4 + mi][ni] = __builtin_amdgcn_mfma_f32_16x16x32_bf16(
                        a[mi][kk], b[ni][kk], acc[4 + mi][ni], 0, 0, 0);
        __builtin_amdgcn_s_setprio(0);
    }
#undef STAGE_TILE

    // ---- fused ACT epilogue ----
    // D layout: col = l16, row = quad*4 + reg (within each 16x16 tile)
    const int colBase = gn + 64 * wc;
    float btc[4], PTc[KHOP][4];
#pragma unroll
    for (int ni = 0; ni < 4; ni++) {
        int col = colBase + 16 * ni + l16;
        btc[ni] = bt[col];
#pragma unroll
        for (int k = 0; k < KHOP; k++) PTc[k][ni] = PT[k * Hdim + col];
    }
    const int rowBase = gm + 128 * wr;
#pragma unroll
    for (int mi = 0; mi < 8; mi++) {
        int r0 = rowBase + 16 * mi + quad * 4;
        float Sr[4], Wr[KHOP][4];
#pragma unroll
        for (int reg = 0; reg < 4; reg++) Sr[reg] = SS[r0 + reg];
#pragma unroll
        for (int k = 0; k < KHOP; k++)
#pragma unroll
            for (int reg = 0; reg < 4; reg++) Wr[k][reg] = WW[k * Ntok + r0 + reg];
#pragma unroll
        for (int ni = 0; ni < 4; ni++) {
            int col = colBase + 16 * ni + l16;
#pragma unroll
            for (int reg = 0; reg < 4; reg++) {
                float v = Sr[reg] * (acc[mi][ni][reg] + btc[ni]);
#pragma unroll
                for (int k = 0; k < KHOP; k++) v += Wr[k][reg] * PTc[k][ni];
                out[(size_t)(r0 + reg) * Hdim + col] = v;
            }
        }
    }
}

extern "C" void kernel_launch(void* const* d_in, const int* in_sizes, int n_in,
                              void* d_out, int out_size, void* d_ws, size_t ws_size,
                              hipStream_t stream) {
    const float* inp   = (const float*)d_in[0];
    const float* tenc  = (const float*)d_in[1];
    const float* pos   = (const float*)d_in[2];
    const float* gamma = (const float*)d_in[3];
    const float* beta  = (const float*)d_in[4];
    const float* wp    = (const float*)d_in[5];
    const float* bp    = (const float*)d_in[6];
    const float* Wt    = (const float*)d_in[7];
    const float* bt    = (const float*)d_in[8];
    float* out = (float*)d_out;

    float* W = (float*)d_ws;
    float* kst = W;                         // 64 floats
    float* gwArr = W + 64;                  // 1024 floats (gamma*wp)
    float* PT  = gwArr + Hdim;              // 12*1024
    float* SS  = PT + KHOP * Hdim;          // 16384
    float* WW  = SS + Ntok;                 // 12*16384
    u16* WtBF  = (u16*)(WW + KHOP * Ntok);  // 1M u16 = 2MB (8B-aligned)
    u16* baseBF = WtBF + (size_t)Hdim * Hdim; // 16M u16 = 32MB

    static bool attr_done = false;
    if (!attr_done) {
        (void)hipFuncSetAttribute((const void*)gemm_bf16,
                                  hipFuncAttributeMaxDynamicSharedMemorySize,
                                  131072);
        attr_done = true;
    }

    kstats_kernel<<<1, 64, 0, stream>>>(pos, gamma, beta, wp, kst, gwArr);
    ptwt_kernel<<<1024, 256, 0, stream>>>(pos, Wt, PT, WtBF);
    token_kernel<<<1024, 256, 0, stream>>>(inp, tenc, pos, gwArr, bp, kst,
                                           SS, WW, out + (size_t)Ntok * Hdim, baseBF);
    gemm_bf16<<<dim3(64, 4), 512, 131072, stream>>>(baseBF, WtBF, bt, PT, SS, WW, out);
}

// Round 3
// 193.175 us; speedup vs baseline: 1.2509x; 1.2509x over previous
//
#include <hip/hip_runtime.h>

// ACT module decomposition:
//   base = inputs + time_enc; state_k = base + pos_enc[k]
//   LN stats + halting collapse to per-token scalars (fp32, bit-exact branches)
//   tstate_k = Bt + Pt_k + bt with Bt = base@Wt^T  (ONE gemm, bf16 MFMA)
//   prev = S*(Bt+bt) + sum_k w_k*Pt_k
//
// Round-6 changes:
//   - kstats parallelized: 13 blocks (k-blocks 0..11 + gw/bw block 12), each
//     with the ORIGINAL per-lane accumulation + butterfly order (bit-exact);
//     merged into ptwt's launch (kstats blocks first -> hidden under ptwt).
//     Theory: single-wave kstats was the constant ~110us invisible cost.
//   - token_kernel: LDS sPos restored (r2's global-pos variant collapsed to
//     36 VGPR and serialized at L2 latency); widened to 512 thr / 32 tokens /
//     512 blocks -> uniform 2 blocks/CU = 16 waves/CU (vs 12 before).
//   - gemm unchanged (256x256 pipelined, counted vmcnt(8)).

#define Hdim 1024
#define Ntok 16384
#define Tdim 2048
#define KHOP 12

typedef unsigned short u16;
typedef __attribute__((ext_vector_type(8))) short bf16x8;
typedef __attribute__((ext_vector_type(4))) float floatx4;
struct __align__(8) u16x4 { u16 x, y, z, w; };

static __device__ inline u16 f2bf(float f) {
    union { float f; unsigned u; } x; x.f = f;
    unsigned r = x.u + 0x7FFFu + ((x.u >> 16) & 1u);   // RNE
    return (u16)(r >> 16);
}

// -------- kernel A: kstats (blocks 0..12) + PT/WtBF rows (blocks 13..1036) --
// kst layout: [0..11] mu_pk, [12..23] ssp_k, [24..35] e_k, [36] gw, [37] bw
// kstats blocks use 64 threads; per-value reduction order is bit-identical to
// the original single-block kernel (lane partials i=0..15, then butterfly).
__global__ __launch_bounds__(256)
void ptwt_kernel(const float* __restrict__ pos,
                 const float* __restrict__ gamma,
                 const float* __restrict__ beta,
                 const float* __restrict__ wp,
                 const float* __restrict__ Wt,
                 float* __restrict__ kst,
                 float* __restrict__ gwArr,
                 float* __restrict__ PT,
                 u16* __restrict__ WtBF) {
    if (blockIdx.x < 13) {
        int lane = threadIdx.x;
        if (lane >= 64) return;
        int b = blockIdx.x;
        if (b == 12) {
            float gw = 0.f, bw = 0.f;
#pragma unroll
            for (int i = 0; i < 16; i++) {
                int h = lane + 64 * i;
                float g = gamma[h] * wp[h];
                gwArr[h] = g;
                gw += g;
                bw += beta[h] * wp[h];
            }
            for (int off = 32; off > 0; off >>= 1) {
                gw += __shfl_xor(gw, off);
                bw += __shfl_xor(bw, off);
            }
            if (lane == 0) { kst[36] = gw; kst[37] = bw; }
        } else {
            int k = b;
            float gw = 0.f;
#pragma unroll
            for (int i = 0; i < 16; i++) {
                int h = lane + 64 * i;
                gw += gamma[h] * wp[h];
            }
            for (int off = 32; off > 0; off >>= 1) gw += __shfl_xor(gw, off);
            float s = 0.f, ss = 0.f, pg = 0.f;
#pragma unroll
            for (int i = 0; i < 16; i++) {
                int h = lane + 64 * i;
                float v = pos[k * Hdim + h];
                s += v; ss += v * v; pg += v * gamma[h] * wp[h];
            }
            for (int off = 32; off > 0; off >>= 1) {
                s += __shfl_xor(s, off);
                ss += __shfl_xor(ss, off);
                pg += __shfl_xor(pg, off);
            }
            if (lane == 0) {
                float mu = s * (1.0f / Hdim);
                kst[k] = mu;
                kst[12 + k] = ss - (float)Hdim * mu * mu;
                kst[24 + k] = pg - mu * gw;
            }
        }
        return;
    }

    // ---- PT[k][o] = sum_h pos[k,h]*Wt[o,h]  +  Wt->bf16 row ----
    __shared__ float red[4][KHOP];
    int o = blockIdx.x - 13;
    int t = threadIdx.x, wave = t >> 6, lane = t & 63;

    float4 w = ((const float4*)(Wt + (size_t)o * Hdim))[t];
    u16x4 ob; ob.x = f2bf(w.x); ob.y = f2bf(w.y); ob.z = f2bf(w.z); ob.w = f2bf(w.w);
    ((u16x4*)(WtBF + (size_t)o * Hdim))[t] = ob;

    const float4* pos4 = (const float4*)pos;
    float acc[KHOP];
#pragma unroll
    for (int k = 0; k < KHOP; k++) {
        float4 p = pos4[k * 256 + t];
        acc[k] = w.x * p.x + w.y * p.y + w.z * p.z + w.w * p.w;
    }
#pragma unroll
    for (int k = 0; k < KHOP; k++)
        for (int off = 32; off > 0; off >>= 1) acc[k] += __shfl_xor(acc[k], off);
    if (lane == 0) {
#pragma unroll
        for (int k = 0; k < KHOP; k++) red[wave][k] = acc[k];
    }
    __syncthreads();
    if (t < KHOP)
        PT[t * Hdim + o] = red[0][t] + red[1][t] + red[2][t] + red[3][t];
}

// ---------------- kernel B: token stats + halting + base->bf16 ----------------
// 512 blocks x 512 thr; block = 32 tokens (8 waves x 4 tokens), single pass.
// Wave handles 4 tokens: 16 lanes per token, 64 elems (16 float4) per lane.
// pos staged in 48KB LDS (proven r1 structure); 2 blocks/CU = 16 waves/CU.
__global__ __launch_bounds__(512)
void token_kernel(const float* __restrict__ inp, const float* __restrict__ tenc,
                  const float* __restrict__ pos, const float* __restrict__ gwArr,
                  const float* __restrict__ bp, const float* __restrict__ kst,
                  float* __restrict__ SS, float* __restrict__ WW,
                  float* __restrict__ tail, u16* __restrict__ baseBF) {
    __shared__ float sPos[KHOP * Hdim];   // 48 KB
    int t = threadIdx.x;
    for (int i = t; i < KHOP * Hdim; i += 512) sPos[i] = pos[i];
    __syncthreads();

    int wave = t >> 6, lane = t & 63;
    int grp = lane >> 4, s = lane & 15;
    int n = blockIdx.x * 32 + wave * 4 + grp;

    const float4* ip4 = (const float4*)(inp + (size_t)n * Hdim);
    const float4* tp4 = (const float4*)(tenc + (size_t)(n & (Tdim - 1)) * Hdim);
    u16x4* ob4 = (u16x4*)(baseBF + (size_t)n * Hdim);
    const float4* gw4 = (const float4*)gwArr;

    float sm = 0.f, ss = 0.f, d1 = 0.f;
    float dk[KHOP];
#pragma unroll
    for (int k = 0; k < KHOP; k++) dk[k] = 0.f;

#pragma unroll
    for (int i = 0; i < 16; i++) {
        int idx = s + 16 * i;          // float4 index within the token row
        float4 a = ip4[idx], b = tp4[idx];
        float4 v = make_float4(a.x + b.x, a.y + b.y, a.z + b.z, a.w + b.w);
        u16x4 o; o.x = f2bf(v.x); o.y = f2bf(v.y); o.z = f2bf(v.z); o.w = f2bf(v.w);
        ob4[idx] = o;
        sm += v.x + v.y + v.z + v.w;
        ss += v.x * v.x + v.y * v.y + v.z * v.z + v.w * v.w;
        float4 g = gw4[idx];           // global, L1-resident (4 KB shared)
        d1 += v.x * g.x + v.y * g.y + v.z * g.z + v.w * g.w;
        int h = idx * 4;
#pragma unroll
        for (int k = 0; k < KHOP; k++) {
            float4 p = *(const float4*)&sPos[k * Hdim + h];
            dk[k] += v.x * p.x + v.y * p.y + v.z * p.z + v.w * p.w;
        }
    }
    // reduce across the 16 lanes of this token's group
#pragma unroll
    for (int off = 8; off > 0; off >>= 1) {
        sm += __shfl_xor(sm, off);
        ss += __shfl_xor(ss, off);
        d1 += __shfl_xor(d1, off);
#pragma unroll
        for (int k = 0; k < KHOP; k++) dk[k] += __shfl_xor(dk[k], off);
    }

    if (s == 0) {
        float gwv = kst[36], bwv = kst[37], bpv = bp[0];
        float mu = sm * (1.0f / Hdim);
        float ssb = ss - (float)Hdim * mu * mu;
        float hp = 0.f, rem = 0.f, nu = 0.f;
        float uw[KHOP];
#pragma unroll
        for (int k = 0; k < KHOP; k++) {
            float mup = kst[k], sspk = kst[12 + k], ek = kst[24 + k];
            float ck = dk[k] - (float)Hdim * mu * mup;
            float var = (ssb + sspk + 2.0f * ck) * (1.0f / Hdim);
            float inv = 1.0f / sqrtf(var + 1e-5f);
            float logit = inv * (d1 - mu * gwv + ek) + bwv + bpv;
            float p = 1.0f / (1.0f + expf(-logit));
            float sr = (hp < 1.0f) ? 1.0f : 0.0f;
            float acc = hp + p * sr;
            float nh = (acc > 0.9f) ? sr : 0.0f;
            float sr2 = (acc <= 0.9f) ? sr : 0.0f;
            hp += p * sr2;
            rem += nh * (1.0f - hp);
            hp += nh * rem;
            nu += sr2 + nh;
            uw[k] = p * sr2 + nh * rem;
        }
        float prod = 1.f, S = 0.f;
        float w[KHOP];
#pragma unroll
        for (int k = KHOP - 1; k >= 0; k--) {
            w[k] = uw[k] * prod;
            prod *= (1.0f - uw[k]);
            S += w[k];
        }
        SS[n] = S;
#pragma unroll
        for (int k = 0; k < KHOP; k++) WW[k * Ntok + n] = w[k];
        tail[n] = rem;
        tail[Ntok + n] = nu;
    }
}

// ---------------- kernel C: pipelined bf16 MFMA GEMM 256x256xBK64 ------------
// A = baseBF [M=16384, K=1024], Bt = WtBF [N=1024, K=1024] (both K-contiguous)
// out[m,o] = S[m]*(A@Bt^T + bt[o]) + sum_k WW[k][m]*PT[k][o]
//
// LDS (dynamic, 128KB): A slots at byte 0 / 32768, B slots at 65536 / 98304.
// Per slot: [256 rows][64 cols] bf16, row = 8 chunks of 16B; LDS chunk c of
// row r holds global chunk c ^ (r&7)  (involution; read applies same XOR).
// K-loop: 16 K-tiles; tile t+2 staged during group t+1; entry wait vmcnt(8)
// keeps the younger tile's 8 loads in flight across the barrier.
__global__ __launch_bounds__(512, 2)
void gemm_bf16(const u16* __restrict__ A, const u16* __restrict__ Bt,
               const float* __restrict__ bt, const float* __restrict__ PT,
               const float* __restrict__ SS, const float* __restrict__ WW,
               float* __restrict__ out) {
    extern __shared__ u16 lds[];   // 65536 u16 = 128 KB
    const int tid = threadIdx.x;
    const int bm = blockIdx.x;     // 0..63  (M tiles) — linear%8 == bm%8
    const int bn = blockIdx.y;     // 0..3   (N tiles) — A-panel siblings share XCD
    const int gm = bm * 256, gn = bn * 256;

    // ---- staging constants: thread t -> row sr=t>>3 (+64*i), chunk t&7 ----
    const int sr = tid >> 3;
    const int gchunk = ((tid & 7) ^ (sr & 7)) << 3;   // element offset in row
    const u16* aStage = A + (size_t)(gm + sr) * Hdim + gchunk;
    const u16* bStage = Bt + (size_t)(gn + sr) * Hdim + gchunk;
    char* ldsA = (char*)lds + (size_t)tid * 16;            // + s*32768 + i*8192
    char* ldsB = (char*)lds + 65536 + (size_t)tid * 16;

#define STAGE_TILE(kt_)                                                          \
    do {                                                                         \
        const int s_ = (kt_) & 1;                                                \
        const u16* ap_ = aStage + (kt_) * 64;                                    \
        const u16* bp_ = bStage + (kt_) * 64;                                    \
        char* la_ = ldsA + s_ * 32768;                                           \
        char* lb_ = ldsB + s_ * 32768;                                           \
        _Pragma("unroll")                                                        \
        for (int i_ = 0; i_ < 4; i_++) {                                         \
            __builtin_amdgcn_global_load_lds(                                    \
                (const __attribute__((address_space(1))) void*)(ap_ + (size_t)i_ * 64 * Hdim), \
                (__attribute__((address_space(3))) void*)(la_ + i_ * 8192), 16, 0, 0); \
            __builtin_amdgcn_global_load_lds(                                    \
                (const __attribute__((address_space(1))) void*)(bp_ + (size_t)i_ * 64 * Hdim), \
                (__attribute__((address_space(3))) void*)(lb_ + i_ * 8192), 16, 0, 0); \
        }                                                                        \
    } while (0)

    // ---- prologue: tiles 0 and 1 in flight (16 loads) ----
    STAGE_TILE(0);
    STAGE_TILE(1);

    const int wave = tid >> 6, lane = tid & 63;
    const int wr = wave >> 2, wc = wave & 3;       // 2x4 wave grid, 128x64 each
    const int quad = lane >> 4, l16 = lane & 15;
    const int xorl = l16 & 7;
    const int pos0 = ((quad ^ xorl) << 3);         // kk=0 chunk position (elems)
    const int pos1 = (((4 + quad) ^ xorl) << 3);   // kk=1
    const u16* aRd = lds + (size_t)(128 * wr + l16) * 64;
    const u16* bRd = lds + 32768 + (size_t)(64 * wc + l16) * 64;

    floatx4 acc[8][4];
#pragma unroll
    for (int i = 0; i < 8; i++)
#pragma unroll
        for (int j = 0; j < 4; j++) acc[i][j] = (floatx4)0.f;

#pragma unroll 2
    for (int kt = 0; kt < 16; kt++) {
        const int s = kt & 1;
        if (kt < 15) { asm volatile("s_waitcnt vmcnt(8)" ::: "memory"); }
        else         { asm volatile("s_waitcnt vmcnt(0)" ::: "memory"); }
        asm volatile("s_barrier" ::: "memory");    // tile kt fully in LDS

        const u16* aS = aRd + s * 16384;
        const u16* bS = bRd + s * 16384;
        bf16x8 a[4][2], b[4][2];
#pragma unroll
        for (int ni = 0; ni < 4; ni++) {
            b[ni][0] = *(const bf16x8*)&bS[ni * 1024 + pos0];
            b[ni][1] = *(const bf16x8*)&bS[ni * 1024 + pos1];
        }
#pragma unroll
        for (int mi = 0; mi < 4; mi++) {
            a[mi][0] = *(const bf16x8*)&aS[mi * 1024 + pos0];
            a[mi][1] = *(const bf16x8*)&aS[mi * 1024 + pos1];
        }
        __builtin_amdgcn_s_setprio(1);
#pragma unroll
        for (int kk = 0; kk < 2; kk++)
#pragma unroll
            for (int mi = 0; mi < 4; mi++)
#pragma unroll
                for (int ni = 0; ni < 4; ni++)
                    acc[mi][ni] = __builtin_amdgcn_mfma_f32_16x16x32_bf16(
                        a[mi][kk], b[ni][kk], acc[mi][ni], 0, 0, 0);
        __builtin_amdgcn_s_setprio(0);

        // rows 128..255 of the A half this wave owns
#pragma unroll
        for (int mi = 0; mi < 4; mi++) {
            a[mi][0] = *(const bf16x8*)&aS[4096 + mi * 1024 + pos0];
            a[mi][1] = *(const bf16x8*)&aS[4096 + mi * 1024 + pos1];
        }
        // all reads of slot s issued by every wave -> safe to overwrite:
        // stage loads land >=~250cy after issue, reads complete in ~50cy.
        asm volatile("s_barrier" ::: "memory");
        if (kt < 14) STAGE_TILE(kt + 2);
        __builtin_amdgcn_s_setprio(1);
#pragma unroll
        for (int kk = 0; kk < 2; kk++)
#pragma unroll
            for (int mi = 0; mi < 4; mi++)
#pragma unroll
                for (int ni = 0; ni < 4; ni++)
                    acc[4 + mi][ni] = __builtin_amdgcn_mfma_f32_16x16x32_bf16(
                        a[mi][kk], b[ni][kk], acc[4 + mi][ni], 0, 0, 0);
        __builtin_amdgcn_s_setprio(0);
    }
#undef STAGE_TILE

    // ---- fused ACT epilogue ----
    // D layout: col = l16, row = quad*4 + reg (within each 16x16 tile)
    const int colBase = gn + 64 * wc;
    float btc[4], PTc[KHOP][4];
#pragma unroll
    for (int ni = 0; ni < 4; ni++) {
        int col = colBase + 16 * ni + l16;
        btc[ni] = bt[col];
#pragma unroll
        for (int k = 0; k < KHOP; k++) PTc[k][ni] = PT[k * Hdim + col];
    }
    const int rowBase = gm + 128 * wr;
#pragma unroll
    for (int mi = 0; mi < 8; mi++) {
        int r0 = rowBase + 16 * mi + quad * 4;
        float Sr[4], Wr[KHOP][4];
#pragma unroll
        for (int reg = 0; reg < 4; reg++) Sr[reg] = SS[r0 + reg];
#pragma unroll
        for (int k = 0; k < KHOP; k++)
#pragma unroll
            for (int reg = 0; reg < 4; reg++) Wr[k][reg] = WW[k * Ntok + r0 + reg];
#pragma unroll
        for (int ni = 0; ni < 4; ni++) {
            int col = colBase + 16 * ni + l16;
#pragma unroll
            for (int reg = 0; reg < 4; reg++) {
                float v = Sr[reg] * (acc[mi][ni][reg] + btc[ni]);
#pragma unroll
                for (int k = 0; k < KHOP; k++) v += Wr[k][reg] * PTc[k][ni];
                out[(size_t)(r0 + reg) * Hdim + col] = v;
            }
        }
    }
}

extern "C" void kernel_launch(void* const* d_in, const int* in_sizes, int n_in,
                              void* d_out, int out_size, void* d_ws, size_t ws_size,
                              hipStream_t stream) {
    const float* inp   = (const float*)d_in[0];
    const float* tenc  = (const float*)d_in[1];
    const float* pos   = (const float*)d_in[2];
    const float* gamma = (const float*)d_in[3];
    const float* beta  = (const float*)d_in[4];
    const float* wp    = (const float*)d_in[5];
    const float* bp    = (const float*)d_in[6];
    const float* Wt    = (const float*)d_in[7];
    const float* bt    = (const float*)d_in[8];
    float* out = (float*)d_out;

    float* W = (float*)d_ws;
    float* kst = W;                         // 64 floats
    float* gwArr = W + 64;                  // 1024 floats (gamma*wp)
    float* PT  = gwArr + Hdim;              // 12*1024
    float* SS  = PT + KHOP * Hdim;          // 16384
    float* WW  = SS + Ntok;                 // 12*16384
    u16* WtBF  = (u16*)(WW + KHOP * Ntok);  // 1M u16 = 2MB (8B-aligned)
    u16* baseBF = WtBF + (size_t)Hdim * Hdim; // 16M u16 = 32MB

    static bool attr_done = false;
    if (!attr_done) {
        (void)hipFuncSetAttribute((const void*)gemm_bf16,
                                  hipFuncAttributeMaxDynamicSharedMemorySize,
                                  131072);
        attr_done = true;
    }

    ptwt_kernel<<<1037, 256, 0, stream>>>(pos, gamma, beta, wp, Wt,
                                          kst, gwArr, PT, WtBF);
    token_kernel<<<512, 512, 0, stream>>>(inp, tenc, pos, gwArr, bp, kst,
                                          SS, WW, out + (size_t)Ntok * Hdim, baseBF);
    gemm_bf16<<<dim3(64, 4), 512, 131072, stream>>>(baseBF, WtBF, bt, PT, SS, WW, out);
}